// Round 10
// baseline (476.649 us; speedup 1.0000x reference)
//
#include <hip/hip_runtime.h>
#include <math.h>

#define N_NODES 20000
#define N_EDGES 640000
#define ETOT (N_EDGES + N_NODES)
#define HC 256
#define NLAYER 3
#define NBATCH 16
#define GEPS 1e-5f
#define NSLOT 64

typedef unsigned short u16;
typedef unsigned int u32;
typedef __attribute__((ext_vector_type(8))) short short8;
typedef __attribute__((ext_vector_type(4))) float floatx4;

__device__ __forceinline__ u16 f2bf(float f) {
    u32 u = __float_as_uint(f);
    u32 r = (u + 0x7FFFu + ((u >> 16) & 1u)) >> 16;
    return (u16)r;
}

__device__ __forceinline__ float4 bf2f4(uint2 u) {
    float4 r;
    r.x = __uint_as_float(u.x << 16);
    r.y = __uint_as_float(u.x & 0xFFFF0000u);
    r.z = __uint_as_float(u.y << 16);
    r.w = __uint_as_float(u.y & 0xFFFF0000u);
    return r;
}

// VALU-only 16-lane butterfly sum
__device__ __forceinline__ float dpp_red16(float x) {
    x += __int_as_float(__builtin_amdgcn_update_dpp(0, __float_as_int(x), 0xB1, 0xF, 0xF, true));
    x += __int_as_float(__builtin_amdgcn_update_dpp(0, __float_as_int(x), 0x4E, 0xF, 0xF, true));
    x += __int_as_float(__builtin_amdgcn_update_dpp(0, __float_as_int(x), 0x141, 0xF, 0xF, true));
    x += __int_as_float(__builtin_amdgcn_update_dpp(0, __float_as_int(x), 0x140, 0xF, 0xF, true));
    return x;
}

// ---------------- prep: convert x to bf16, transpose W, zero scratch ----------------
// grid: [0,1000) convert, [1000,1384) transpose, [1384,1504) zero

__global__ __launch_bounds__(256) void prep(const float* __restrict__ x, u16* __restrict__ xbf,
                                            const float* __restrict__ Wl, const float* __restrict__ Wr,
                                            u16* __restrict__ WT, uint4* __restrict__ zbase, int zq) {
    int b = blockIdx.x, tid = threadIdx.x;
    if (b < 1000) {
        for (int i = b * 256 + tid; i < 640000; i += 256000) {
            const float4* x4 = (const float4*)x + (size_t)i * 2;
            float4 a = x4[0], c = x4[1];
            u16 o[8] = {f2bf(a.x), f2bf(a.y), f2bf(a.z), f2bf(a.w),
                        f2bf(c.x), f2bf(c.y), f2bf(c.z), f2bf(c.w)};
            ((uint4*)xbf)[i] = *(const uint4*)o;
        }
    } else if (b < 1384) {
        __shared__ float T[32][33];
        int bi = b - 1000;
        int kb = bi & 7, nbk = (bi >> 3) & 15, l = bi >> 7;
        int n0 = nbk * 32, k0 = kb * 32;
        const float* W = ((n0 < 256) ? Wl : Wr) + (size_t)l * 65536;
        int nn = n0 & 255;
        int tx = tid & 31, ty = tid >> 5;
        #pragma unroll
        for (int i = 0; i < 4; ++i)
            T[ty + i * 8][tx] = W[(size_t)(k0 + ty + i * 8) * 256 + nn + tx];
        __syncthreads();
        u16* outw = WT + (size_t)l * 512 * 256;
        #pragma unroll
        for (int i = 0; i < 4; ++i)
            outw[(size_t)(n0 + ty + i * 8) * 256 + k0 + tx] = f2bf(T[tx][ty + i * 8]);
    } else {
        uint4 z = make_uint4(0, 0, 0, 0);
        for (int i = (b - 1384) * 256 + tid; i < zq; i += 120 * 256) zbase[i] = z;
    }
}

// ---------------- CSR build: count / scan / scatter ----------------
// v2: 4 items per thread, phase-split -> 4 independent atomics in flight
// per wave (was 1). These kernels were pure latency-bound (VALUBusy 0.3%).

__global__ __launch_bounds__(256) void count_deg(const int* __restrict__ dst, int* __restrict__ deg) {
    int base = blockIdx.x * 1024 + threadIdx.x;
    int d[4];
    bool act[4];
    #pragma unroll
    for (int k = 0; k < 4; ++k) {
        int e = base + k * 256;
        act[k] = e < N_EDGES;
        d[k] = act[k] ? dst[e] : 0;
    }
    #pragma unroll
    for (int k = 0; k < 4; ++k)
        if (act[k]) atomicAdd(&deg[d[k]], 1);
}

// single-pass scan: each thread owns 20 rows; exclusive scan of (deg+1) -> rowptr/cursor
__global__ __launch_bounds__(1024) void scan_excl(int* __restrict__ data, int* __restrict__ cursor) {
    __shared__ int wsum[16];
    int t = threadIdx.x, lane = t & 63, wid = t >> 6;
    int i0 = t * 20;
    int d[20];
    int tot = 0;
    #pragma unroll
    for (int j = 0; j < 20; ++j) {
        int i = i0 + j;
        int v = (i < N_NODES) ? (data[i] + 1) : 0;  // +1 = self-loop
        d[j] = v;
        tot += v;
    }
    int x = tot;
    #pragma unroll
    for (int off = 1; off < 64; off <<= 1) {
        int tmp = __shfl_up(x, off);
        if (lane >= off) x += tmp;
    }
    if (lane == 63) wsum[wid] = x;
    __syncthreads();
    if (t == 0) {
        int run = 0;
        #pragma unroll
        for (int w = 0; w < 16; ++w) { int tv = wsum[w]; wsum[w] = run; run += tv; }
    }
    __syncthreads();
    int run = wsum[wid] + x - tot;  // exclusive prefix for this thread
    #pragma unroll
    for (int j = 0; j < 20; ++j) {
        int i = i0 + j;
        if (i < N_NODES) { data[i] = run; cursor[i] = run; }
        run += d[j];
    }
    if (t == 0) data[N_NODES] = ETOT;
}

__global__ __launch_bounds__(256) void scatter_edges(const int* __restrict__ src, const int* __restrict__ dst,
                                                     int* __restrict__ cursor, int* __restrict__ col) {
    int base = blockIdx.x * 1024 + threadIdx.x;
    int dsts[4], vals[4], p[4];
    bool act[4];
    #pragma unroll
    for (int k = 0; k < 4; ++k) {
        int i = base + k * 256;
        act[k] = i < ETOT;
        dsts[k] = 0; vals[k] = 0;
        if (i < N_NODES) { dsts[k] = i; vals[k] = i; }            // self-loop
        else if (i < ETOT) {
            int e = i - N_NODES;
            dsts[k] = dst[e]; vals[k] = src[e];
        }
    }
    #pragma unroll
    for (int k = 0; k < 4; ++k)
        if (act[k]) p[k] = atomicAdd(&cursor[dsts[k]], 1);        // 4 atomics in flight
    #pragma unroll
    for (int k = 0; k < 4; ++k)
        if (act[k]) col[p[k]] = vals[k];
}

// ---------------- bf16 MFMA dual GEMM with fused GraphNorm+PReLU on A ----------------
// R7 body (proven). Grid flattened to 640 with XCD co-location swizzle:
// r = (id>>5)*8 + (id&7), s = (id>>3)&3  ->  the 4 col-strips sharing A-rows
// get ids spaced by 8 (same XCD under id%8 round-robin) and adjacent dispatch
// order -> A-rows served from that XCD's L2 for 3 of 4 readers. [verified R9]

__global__ __launch_bounds__(256) void gemm_mfma(
    const u16* __restrict__ Asrc, const float* __restrict__ slots_prev,
    const float* __restrict__ nw, const float* __restrict__ nb, const float* __restrict__ na,
    const float* __restrict__ pa, int prelu_idx, int use_norm,
    const u16* __restrict__ WT,
    const float* __restrict__ b0, const float* __restrict__ b1,
    u16* __restrict__ xlb, u16* __restrict__ xrb) {
    __shared__ u16 As[128][40];
    __shared__ u16 Bs[128][40];
    __shared__ float wcL[256], bbL[256];
    int id = blockIdx.x;
    int rblk = ((id >> 5) << 3) + (id & 7);
    int nstrip = (id >> 3) & 3;              // 0,1 -> xl; 2,3 -> xr
    if (rblk >= 157) return;
    int row0 = rblk * 128;
    int ncol0 = nstrip * 128;
    const float* bias = (nstrip < 2) ? b0 : b1;
    u16* outp = (nstrip < 2) ? xlb : xrb;
    int c0 = (nstrip & 1) * 128;

    int tid = threadIdx.x;
    float ap = 0.f;
    if (use_norm) {
        int c = tid;
        float sum = 0.f, sq = 0.f;
        for (int s = 0; s < NSLOT; ++s) {
            sum += slots_prev[s * 512 + c];
            sq += slots_prev[s * 512 + 256 + c];
        }
        const float invn = 1.f / (float)N_NODES;
        float mean = sum * invn, Eh2 = sq * invn;
        float a = na[c];
        float var = Eh2 - (2.f * a - a * a) * mean * mean;
        float wc = nw[c] * rsqrtf(var + GEPS);
        wcL[c] = wc;
        bbL[c] = nb[c] - a * mean * wc;
        ap = pa[prelu_idx];
        __syncthreads();
    }

    int wave = tid >> 6, lane = tid & 63;
    int wm = (wave & 1) * 64, wn = (wave >> 1) * 64;
    int quad = lane >> 4, l16 = lane & 15;

    floatx4 acc[4][4] = {};

    int sr = tid >> 1;
    int sh = (tid & 1) * 16;

    for (int k0 = 0; k0 < 256; k0 += 32) {
        int gr = row0 + sr;
        uint4 av0 = make_uint4(0, 0, 0, 0), av1 = make_uint4(0, 0, 0, 0);
        if (gr < N_NODES) {
            const u16* p = Asrc + (size_t)gr * 256 + k0 + sh;
            av0 = *(const uint4*)p;
            av1 = *(const uint4*)(p + 8);
        }
        if (use_norm) {
            int kb2 = k0 + sh;
            u16 tmp[16];
            *(uint4*)tmp = av0;
            *(uint4*)(tmp + 8) = av1;
            float4 wv0 = *(const float4*)&wcL[kb2], wv1 = *(const float4*)&wcL[kb2 + 4];
            float4 wv2 = *(const float4*)&wcL[kb2 + 8], wv3 = *(const float4*)&wcL[kb2 + 12];
            float4 bv0 = *(const float4*)&bbL[kb2], bv1 = *(const float4*)&bbL[kb2 + 4];
            float4 bv2 = *(const float4*)&bbL[kb2 + 8], bv3 = *(const float4*)&bbL[kb2 + 12];
            float wvf[16] = {wv0.x, wv0.y, wv0.z, wv0.w, wv1.x, wv1.y, wv1.z, wv1.w,
                             wv2.x, wv2.y, wv2.z, wv2.w, wv3.x, wv3.y, wv3.z, wv3.w};
            float bvf[16] = {bv0.x, bv0.y, bv0.z, bv0.w, bv1.x, bv1.y, bv1.z, bv1.w,
                             bv2.x, bv2.y, bv2.z, bv2.w, bv3.x, bv3.y, bv3.z, bv3.w};
            u16 outv[16];
            #pragma unroll
            for (int j = 0; j < 16; ++j) {
                float vv = __uint_as_float(((u32)tmp[j]) << 16);
                float t2 = vv * wvf[j] + bvf[j];
                t2 = fmaxf(t2, ap * t2);
                outv[j] = f2bf(t2);
            }
            av0 = *(const uint4*)outv;
            av1 = *(const uint4*)(outv + 8);
        }
        const u16* q = WT + (size_t)(ncol0 + sr) * 256 + k0 + sh;
        uint4 bw0 = *(const uint4*)q;
        uint4 bw1 = *(const uint4*)(q + 8);
        *(uint4*)&As[sr][sh] = av0;
        *(uint4*)&As[sr][sh + 8] = av1;
        *(uint4*)&Bs[sr][sh] = bw0;
        *(uint4*)&Bs[sr][sh + 8] = bw1;
        __syncthreads();

        short8 af[4], bfr[4];
        #pragma unroll
        for (int mi = 0; mi < 4; ++mi)
            af[mi] = *(const short8*)&As[wm + mi * 16 + l16][quad * 8];
        #pragma unroll
        for (int ni = 0; ni < 4; ++ni)
            bfr[ni] = *(const short8*)&Bs[wn + ni * 16 + l16][quad * 8];
        #pragma unroll
        for (int mi = 0; mi < 4; ++mi)
            #pragma unroll
            for (int ni = 0; ni < 4; ++ni)
                acc[mi][ni] = __builtin_amdgcn_mfma_f32_16x16x32_bf16(af[mi], bfr[ni], acc[mi][ni], 0, 0, 0);
        __syncthreads();
    }

    // C/D layout: col = lane&15, row = quad*4 + reg
    #pragma unroll
    for (int ni = 0; ni < 4; ++ni) {
        int col = c0 + wn + ni * 16 + l16;
        float bv = bias[col];
        #pragma unroll
        for (int mi = 0; mi < 4; ++mi) {
            int gr = row0 + wm + mi * 16 + quad * 4;
            #pragma unroll
            for (int r = 0; r < 4; ++r) {
                if (gr + r < N_NODES)
                    outp[(size_t)(gr + r) * 256 + col] = f2bf(acc[mi][ni][r] + bv);
            }
        }
    }
}

// ---------------- fused GATv2 aggregation + column stats ----------------
// EXACT R1 (v2) body — best-measured variant (62.5-63.7 us). gat_agg is at
// its beyond-L2 traffic floor (~113 MB @ ~2 TB/s); variants v3-v8 all landed
// 62-68 us. Do not touch.

__device__ __forceinline__ void gat_load8(const int* __restrict__ col, int j, int lane,
                                          const u16* __restrict__ xlb, uint2 (&rr)[8]) {
    int cv = col[j + (lane & 7)];   // one coalesced load carries all 8 indices
    #pragma unroll
    for (int u = 0; u < 8; ++u) {
        int s = __builtin_amdgcn_readlane(cv, u);   // SGPR index -> SALU base addr
        rr[u] = *((const uint2*)(xlb + ((size_t)(u32)s << 8)) + lane);
    }
}

__device__ __forceinline__ void gat_comp8(const uint2 (&rr)[8], const float4& xrv, const float4& attv,
                                          float& denom, float4& acc) {
    #pragma unroll
    for (int u = 0; u < 8; ++u) {
        float4 a = bf2f4(rr[u]);
        float vx = a.x + xrv.x, vy = a.y + xrv.y;
        float vz = a.z + xrv.z, vw = a.w + xrv.w;
        vx = fmaxf(vx, 0.2f * vx);
        vy = fmaxf(vy, 0.2f * vy);
        vz = fmaxf(vz, 0.2f * vz);
        vw = fmaxf(vw, 0.2f * vw);
        float p = vx * attv.x + vy * attv.y + vz * attv.z + vw * attv.w;
        p = dpp_red16(p);
        float w = exp2f(p);          // att prescaled by log2(e): bare v_exp_f32
        denom += w;
        acc.x += w * a.x; acc.y += w * a.y;
        acc.z += w * a.z; acc.w += w * a.w;
    }
}

__global__ __launch_bounds__(256) void gat_agg(
    const u16* __restrict__ xlb, const u16* __restrict__ xrb,
    const int* __restrict__ rowptr, const int* __restrict__ col,
    const float* __restrict__ att_l, const float* __restrict__ bias_l,
    u16* __restrict__ hB, float* __restrict__ slot) {
    __shared__ float sred[4][520];
    int wid = threadIdx.x >> 6, lane = threadIdx.x & 63;
    int node = blockIdx.x * 4 + wid;   // 5000*4 == 20000 exactly
    const float LOG2E = 1.4426950408889634f;
    float4 attv = ((const float4*)att_l)[lane];
    attv.x *= LOG2E; attv.y *= LOG2E; attv.z *= LOG2E; attv.w *= LOG2E;
    float4 xrv = bf2f4(((const uint2*)xrb)[(size_t)node * 64 + lane]);
    int beg = __builtin_amdgcn_readfirstlane(rowptr[node]);
    int end = __builtin_amdgcn_readfirstlane(rowptr[node + 1]);

    float denom = 0.f;
    float4 acc = make_float4(0.f, 0.f, 0.f, 0.f);

    int nb = (end - beg) >> 3;   // full 8-edge batches
    int j = beg;
    uint2 rA[8], rB[8];
    if (nb > 0) gat_load8(col, j, lane, xlb, rA);
    int b = 0;
    while (b < nb) {
        if (b + 1 < nb) gat_load8(col, j + 8, lane, xlb, rB);   // prefetch next batch
        gat_comp8(rA, xrv, attv, denom, acc);
        ++b; j += 8;
        if (b < nb) {
            if (b + 1 < nb) gat_load8(col, j + 8, lane, xlb, rA);
            gat_comp8(rB, xrv, attv, denom, acc);
            ++b; j += 8;
        }
    }
    for (; j < end; ++j) {
        int s = __builtin_amdgcn_readfirstlane(col[j]);
        uint2 r = *((const uint2*)(xlb + ((size_t)(u32)s << 8)) + lane);
        float4 a = bf2f4(r);
        float vx = a.x + xrv.x, vy = a.y + xrv.y;
        float vz = a.z + xrv.z, vw = a.w + xrv.w;
        vx = fmaxf(vx, 0.2f * vx);
        vy = fmaxf(vy, 0.2f * vy);
        vz = fmaxf(vz, 0.2f * vz);
        vw = fmaxf(vw, 0.2f * vw);
        float p = vx * attv.x + vy * attv.y + vz * attv.z + vw * attv.w;
        p = dpp_red16(p);
        float w = exp2f(p);
        denom += w;
        acc.x += w * a.x; acc.y += w * a.y; acc.z += w * a.z; acc.w += w * a.w;
    }

    float inv = 1.f / denom;
    float4 b4 = ((const float4*)bias_l)[lane];
    float4 o;
    o.x = acc.x * inv + b4.x; o.y = acc.y * inv + b4.y;
    o.z = acc.z * inv + b4.z; o.w = acc.w * inv + b4.w;
    u16 ob[4] = {f2bf(o.x), f2bf(o.y), f2bf(o.z), f2bf(o.w)};
    ((uint2*)hB)[(size_t)node * 64 + lane] = *(const uint2*)ob;

    int cb2 = lane * 4;
    sred[wid][cb2 + 0] = o.x; sred[wid][cb2 + 1] = o.y;
    sred[wid][cb2 + 2] = o.z; sred[wid][cb2 + 3] = o.w;
    sred[wid][256 + cb2 + 0] = o.x * o.x; sred[wid][256 + cb2 + 1] = o.y * o.y;
    sred[wid][256 + cb2 + 2] = o.z * o.z; sred[wid][256 + cb2 + 3] = o.w * o.w;
    __syncthreads();
    int t = threadIdx.x;
    #pragma unroll
    for (int h = 0; h < 2; ++h) {
        int idx = t + h * 256;
        float s = sred[0][idx] + sred[1][idx] + sred[2][idx] + sred[3][idx];
        atomicAdd(&slot[(blockIdx.x & (NSLOT - 1)) * 512 + idx], s);
    }
}

// ---------------- pool with fused final GraphNorm+PReLU ----------------

__global__ __launch_bounds__(256) void pool_kernel(const u16* __restrict__ hB,
                                                   const int* __restrict__ batch,
                                                   const float* __restrict__ slots2,
                                                   const float* __restrict__ nw, const float* __restrict__ nb,
                                                   const float* __restrict__ na, const float* __restrict__ pa,
                                                   float* __restrict__ pooled) {
    __shared__ float accs[NBATCH][256];
    int c = threadIdx.x;
    float sum = 0.f, sq = 0.f;
    for (int s = 0; s < NSLOT; ++s) {
        sum += slots2[s * 512 + c];
        sq += slots2[s * 512 + 256 + c];
    }
    const float invn = 1.f / (float)N_NODES;
    float mean = sum * invn, Eh2 = sq * invn;
    float a = na[c];
    float var = Eh2 - (2.f * a - a * a) * mean * mean;
    float wc = nw[c] * rsqrtf(var + GEPS);
    float bb = nb[c] - a * mean * wc;
    float ap = pa[2];

    #pragma unroll
    for (int b = 0; b < NBATCH; ++b) accs[b][c] = 0.f;
    int r0 = blockIdx.x * 100;
    int r1 = min(N_NODES, r0 + 100);
    for (int i = r0; i < r1; ++i) {
        float v = __uint_as_float(((u32)hB[(size_t)i * 256 + c]) << 16);
        v = v * wc + bb;
        v = fmaxf(v, ap * v);
        accs[batch[i]][c] += v;
    }
    int bmin = batch[r0], bmax = batch[r1 - 1];
    for (int b = bmin; b <= bmax; ++b) atomicAdd(&pooled[b * 256 + c], accs[b][c]);
}

// ---------------- FC with fused pooled GraphNorm: 16 blocks ----------------

__global__ __launch_bounds__(256) void fc_kernel(const float* __restrict__ pooled,
                                                 const float* __restrict__ nw, const float* __restrict__ nb,
                                                 const float* __restrict__ na,
                                                 const float* __restrict__ fcW, const float* __restrict__ fcb,
                                                 float* __restrict__ out) {
    __shared__ float pnl[256];
    __shared__ float part[128];
    int b = blockIdx.x;
    int t = threadIdx.x;
    float mean = 0.f, sq = 0.f;
    #pragma unroll
    for (int i = 0; i < NBATCH; ++i) {
        float v = pooled[i * 256 + t];
        mean += v; sq += v * v;
    }
    mean *= (1.f / NBATCH); sq *= (1.f / NBATCH);
    float a = na[t];
    float var = sq - (2.f * a - a * a) * mean * mean;
    float wc = nw[t] * rsqrtf(var + GEPS);
    float bb = nb[t] - a * mean * wc;
    pnl[t] = pooled[b * 256 + t] * wc + bb;
    __syncthreads();
    int o = t & 127, half = t >> 7;
    float s = 0.f;
    int kbase = half * 128;
    #pragma unroll 8
    for (int k = 0; k < 128; ++k)
        s += pnl[kbase + k] * fcW[(kbase + k) * 128 + o];
    if (half == 1) part[o] = s;
    __syncthreads();
    if (half == 0) out[b * 128 + o] = s + part[o] + fcb[o];
}

// ---------------- launch ----------------

extern "C" void kernel_launch(void* const* d_in, const int* in_sizes, int n_in,
                              void* d_out, int out_size, void* d_ws, size_t ws_size,
                              hipStream_t stream) {
    const float* x    = (const float*)d_in[0];
    const int*   ei   = (const int*)d_in[1];
    const int*   batch= (const int*)d_in[2];
    const float* Wl   = (const float*)d_in[3];
    const float* bl   = (const float*)d_in[4];
    const float* Wr   = (const float*)d_in[5];
    const float* br   = (const float*)d_in[6];
    const float* att  = (const float*)d_in[7];
    const float* cb   = (const float*)d_in[8];
    const float* pa   = (const float*)d_in[9];
    const float* nw   = (const float*)d_in[10];
    const float* nb   = (const float*)d_in[11];
    const float* na   = (const float*)d_in[12];
    const float* fcW  = (const float*)d_in[13];
    const float* fcb  = (const float*)d_in[14];
    float* out = (float*)d_out;

    char* ws = (char*)d_ws;
    size_t off = 0;
    auto carve = [&](size_t bytes) -> void* {
        void* p = (void*)(ws + off);
        off += (bytes + 255) & ~(size_t)255;
        return p;
    };
    // zero-span region (prep zeroes [rowptr, end-of-pooled))
    size_t z0 = off;
    int*   rowptr = (int*)carve((N_NODES + 1) * sizeof(int));
    float* slots  = (float*)carve((size_t)NLAYER * NSLOT * 512 * sizeof(float));
    float* pooled = (float*)carve(NBATCH * HC * sizeof(float));
    size_t z1 = off;
    // non-zeroed scratch
    int*   cursor = (int*)carve(N_NODES * sizeof(int));
    int*   colidx = (int*)carve((size_t)ETOT * sizeof(int));
    u16*   xlb    = (u16*)carve((size_t)N_NODES * HC * sizeof(u16));
    u16*   xrb    = (u16*)carve((size_t)N_NODES * HC * sizeof(u16));
    u16*   hB     = (u16*)carve((size_t)N_NODES * HC * sizeof(u16));
    u16*   xbf    = (u16*)carve((size_t)N_NODES * HC * sizeof(u16));
    u16*   WT     = (u16*)carve((size_t)NLAYER * 512 * 256 * sizeof(u16));

    int zq = (int)((z1 - z0) / 16);
    const int* srcp = ei;
    const int* dstp = ei + N_EDGES;

    prep<<<1504, 256, 0, stream>>>(x, xbf, Wl, Wr, WT, (uint4*)(ws + z0), zq);
    count_deg<<<(N_EDGES + 1023) / 1024, 256, 0, stream>>>(dstp, rowptr);
    scan_excl<<<1, 1024, 0, stream>>>(rowptr, cursor);
    scatter_edges<<<(ETOT + 1023) / 1024, 256, 0, stream>>>(srcp, dstp, cursor, colidx);

    for (int l = 0; l < NLAYER; ++l) {
        const u16* Asrc = (l == 0) ? xbf : hB;
        const float* slots_prev = slots + (size_t)((l > 0) ? (l - 1) : 0) * NSLOT * 512;
        gemm_mfma<<<640, 256, 0, stream>>>(Asrc, slots_prev, nw, nb, na, pa,
                                           (l > 0) ? (l - 1) : 0, (l > 0) ? 1 : 0,
                                           WT + (size_t)l * 512 * 256,
                                           bl + l * 256, br + l * 256, xlb, xrb);
        gat_agg<<<5000, 256, 0, stream>>>(xlb, xrb, rowptr, colidx, att + l * 256, cb + l * 256,
                                          hB, slots + (size_t)l * NSLOT * 512);
    }
    pool_kernel<<<200, 256, 0, stream>>>(hB, batch, slots + (size_t)2 * NSLOT * 512,
                                         nw, nb, na, pa, pooled);
    fc_kernel<<<NBATCH, 256, 0, stream>>>(pooled, nw, nb, na, fcW, fcb, out);
}

// Round 11
// 463.017 us; speedup vs baseline: 1.0294x; 1.0294x over previous
//
#include <hip/hip_runtime.h>
#include <math.h>

#define N_NODES 20000
#define N_EDGES 640000
#define ETOT (N_EDGES + N_NODES)
#define HC 256
#define NLAYER 3
#define NBATCH 16
#define GEPS 1e-5f
#define NSLOT 64

typedef unsigned short u16;
typedef unsigned int u32;
typedef __attribute__((ext_vector_type(8))) short short8;
typedef __attribute__((ext_vector_type(4))) float floatx4;

__device__ __forceinline__ u16 f2bf(float f) {
    u32 u = __float_as_uint(f);
    u32 r = (u + 0x7FFFu + ((u >> 16) & 1u)) >> 16;
    return (u16)r;
}

__device__ __forceinline__ float4 bf2f4(uint2 u) {
    float4 r;
    r.x = __uint_as_float(u.x << 16);
    r.y = __uint_as_float(u.x & 0xFFFF0000u);
    r.z = __uint_as_float(u.y << 16);
    r.w = __uint_as_float(u.y & 0xFFFF0000u);
    return r;
}

// VALU-only 16-lane butterfly sum
__device__ __forceinline__ float dpp_red16(float x) {
    x += __int_as_float(__builtin_amdgcn_update_dpp(0, __float_as_int(x), 0xB1, 0xF, 0xF, true));
    x += __int_as_float(__builtin_amdgcn_update_dpp(0, __float_as_int(x), 0x4E, 0xF, 0xF, true));
    x += __int_as_float(__builtin_amdgcn_update_dpp(0, __float_as_int(x), 0x141, 0xF, 0xF, true));
    x += __int_as_float(__builtin_amdgcn_update_dpp(0, __float_as_int(x), 0x140, 0xF, 0xF, true));
    return x;
}

// ---------------- prep: convert x to bf16, transpose W, count degrees ----------------
// grid: [0,1000) convert, [1000,1384) transpose, [1384,2009) count_deg
// (zeroing moved to hipMemsetAsync before this kernel; count's atomics are
// latency-bound with ~0 VALU/BW use -> hidden under the BW-bound convert.)

__global__ __launch_bounds__(256) void prep(const float* __restrict__ x, u16* __restrict__ xbf,
                                            const float* __restrict__ Wl, const float* __restrict__ Wr,
                                            u16* __restrict__ WT,
                                            const int* __restrict__ dst, int* __restrict__ deg) {
    int b = blockIdx.x, tid = threadIdx.x;
    if (b < 1000) {
        for (int i = b * 256 + tid; i < 640000; i += 256000) {
            const float4* x4 = (const float4*)x + (size_t)i * 2;
            float4 a = x4[0], c = x4[1];
            u16 o[8] = {f2bf(a.x), f2bf(a.y), f2bf(a.z), f2bf(a.w),
                        f2bf(c.x), f2bf(c.y), f2bf(c.z), f2bf(c.w)};
            ((uint4*)xbf)[i] = *(const uint4*)o;
        }
    } else if (b < 1384) {
        __shared__ float T[32][33];
        int bi = b - 1000;
        int kb = bi & 7, nbk = (bi >> 3) & 15, l = bi >> 7;
        int n0 = nbk * 32, k0 = kb * 32;
        const float* W = ((n0 < 256) ? Wl : Wr) + (size_t)l * 65536;
        int nn = n0 & 255;
        int tx = tid & 31, ty = tid >> 5;
        #pragma unroll
        for (int i = 0; i < 4; ++i)
            T[ty + i * 8][tx] = W[(size_t)(k0 + ty + i * 8) * 256 + nn + tx];
        __syncthreads();
        u16* outw = WT + (size_t)l * 512 * 256;
        #pragma unroll
        for (int i = 0; i < 4; ++i)
            outw[(size_t)(n0 + ty + i * 8) * 256 + k0 + tx] = f2bf(T[tx][ty + i * 8]);
    } else {
        // count_deg: 625 blocks x 1024 edges, 4 independent atomics in flight
        int base = (b - 1384) * 1024 + tid;
        int d[4];
        bool act[4];
        #pragma unroll
        for (int k = 0; k < 4; ++k) {
            int e = base + k * 256;
            act[k] = e < N_EDGES;
            d[k] = act[k] ? dst[e] : 0;
        }
        #pragma unroll
        for (int k = 0; k < 4; ++k)
            if (act[k]) atomicAdd(&deg[d[k]], 1);
    }
}

// single-pass scan: each thread owns 20 rows; exclusive scan of (deg+1) -> rowptr/cursor
__global__ __launch_bounds__(1024) void scan_excl(int* __restrict__ data, int* __restrict__ cursor) {
    __shared__ int wsum[16];
    int t = threadIdx.x, lane = t & 63, wid = t >> 6;
    int i0 = t * 20;
    int d[20];
    int tot = 0;
    #pragma unroll
    for (int j = 0; j < 20; ++j) {
        int i = i0 + j;
        int v = (i < N_NODES) ? (data[i] + 1) : 0;  // +1 = self-loop
        d[j] = v;
        tot += v;
    }
    int x = tot;
    #pragma unroll
    for (int off = 1; off < 64; off <<= 1) {
        int tmp = __shfl_up(x, off);
        if (lane >= off) x += tmp;
    }
    if (lane == 63) wsum[wid] = x;
    __syncthreads();
    if (t == 0) {
        int run = 0;
        #pragma unroll
        for (int w = 0; w < 16; ++w) { int tv = wsum[w]; wsum[w] = run; run += tv; }
    }
    __syncthreads();
    int run = wsum[wid] + x - tot;  // exclusive prefix for this thread
    #pragma unroll
    for (int j = 0; j < 20; ++j) {
        int i = i0 + j;
        if (i < N_NODES) { data[i] = run; cursor[i] = run; }
        run += d[j];
    }
    if (t == 0) data[N_NODES] = ETOT;
}

// ---------------- bf16 MFMA dual GEMM with fused GraphNorm+PReLU on A ----------------
// R7 body (proven) + XCD co-location swizzle [verified R9: -32 us total].
// l=0 launch carries 645 extra blocks (id >= 640) that run scatter_edges —
// independent latency-bound work hidden under the GEMM (colidx consumer gat_agg
// launches after this kernel completes).

__global__ __launch_bounds__(256) void gemm_mfma(
    const u16* __restrict__ Asrc, const float* __restrict__ slots_prev,
    const float* __restrict__ nw, const float* __restrict__ nb, const float* __restrict__ na,
    const float* __restrict__ pa, int prelu_idx, int use_norm,
    const u16* __restrict__ WT,
    const float* __restrict__ b0, const float* __restrict__ b1,
    u16* __restrict__ xlb, u16* __restrict__ xrb,
    const int* __restrict__ srcp, const int* __restrict__ dstp,
    int* __restrict__ cursor, int* __restrict__ colidx) {
    __shared__ u16 As[128][40];
    __shared__ u16 Bs[128][40];
    __shared__ float wcL[256], bbL[256];
    int id = blockIdx.x;
    if (id >= 640) {
        // scatter_edges rider blocks: 645 x 1024 items, 4 atomics in flight
        int base = (id - 640) * 1024 + threadIdx.x;
        int dsts[4], vals[4], p[4];
        bool act[4];
        #pragma unroll
        for (int k = 0; k < 4; ++k) {
            int i = base + k * 256;
            act[k] = i < ETOT;
            dsts[k] = 0; vals[k] = 0;
            if (i < N_NODES) { dsts[k] = i; vals[k] = i; }        // self-loop
            else if (i < ETOT) {
                int e = i - N_NODES;
                dsts[k] = dstp[e]; vals[k] = srcp[e];
            }
        }
        #pragma unroll
        for (int k = 0; k < 4; ++k)
            if (act[k]) p[k] = atomicAdd(&cursor[dsts[k]], 1);
        #pragma unroll
        for (int k = 0; k < 4; ++k)
            if (act[k]) colidx[p[k]] = vals[k];
        return;
    }
    int rblk = ((id >> 5) << 3) + (id & 7);
    int nstrip = (id >> 3) & 3;              // 0,1 -> xl; 2,3 -> xr
    if (rblk >= 157) return;
    int row0 = rblk * 128;
    int ncol0 = nstrip * 128;
    const float* bias = (nstrip < 2) ? b0 : b1;
    u16* outp = (nstrip < 2) ? xlb : xrb;
    int c0 = (nstrip & 1) * 128;

    int tid = threadIdx.x;
    float ap = 0.f;
    if (use_norm) {
        int c = tid;
        float sum = 0.f, sq = 0.f;
        for (int s = 0; s < NSLOT; ++s) {
            sum += slots_prev[s * 512 + c];
            sq += slots_prev[s * 512 + 256 + c];
        }
        const float invn = 1.f / (float)N_NODES;
        float mean = sum * invn, Eh2 = sq * invn;
        float a = na[c];
        float var = Eh2 - (2.f * a - a * a) * mean * mean;
        float wc = nw[c] * rsqrtf(var + GEPS);
        wcL[c] = wc;
        bbL[c] = nb[c] - a * mean * wc;
        ap = pa[prelu_idx];
        __syncthreads();
    }

    int wave = tid >> 6, lane = tid & 63;
    int wm = (wave & 1) * 64, wn = (wave >> 1) * 64;
    int quad = lane >> 4, l16 = lane & 15;

    floatx4 acc[4][4] = {};

    int sr = tid >> 1;
    int sh = (tid & 1) * 16;

    for (int k0 = 0; k0 < 256; k0 += 32) {
        int gr = row0 + sr;
        uint4 av0 = make_uint4(0, 0, 0, 0), av1 = make_uint4(0, 0, 0, 0);
        if (gr < N_NODES) {
            const u16* p = Asrc + (size_t)gr * 256 + k0 + sh;
            av0 = *(const uint4*)p;
            av1 = *(const uint4*)(p + 8);
        }
        if (use_norm) {
            int kb2 = k0 + sh;
            u16 tmp[16];
            *(uint4*)tmp = av0;
            *(uint4*)(tmp + 8) = av1;
            float4 wv0 = *(const float4*)&wcL[kb2], wv1 = *(const float4*)&wcL[kb2 + 4];
            float4 wv2 = *(const float4*)&wcL[kb2 + 8], wv3 = *(const float4*)&wcL[kb2 + 12];
            float4 bv0 = *(const float4*)&bbL[kb2], bv1 = *(const float4*)&bbL[kb2 + 4];
            float4 bv2 = *(const float4*)&bbL[kb2 + 8], bv3 = *(const float4*)&bbL[kb2 + 12];
            float wvf[16] = {wv0.x, wv0.y, wv0.z, wv0.w, wv1.x, wv1.y, wv1.z, wv1.w,
                             wv2.x, wv2.y, wv2.z, wv2.w, wv3.x, wv3.y, wv3.z, wv3.w};
            float bvf[16] = {bv0.x, bv0.y, bv0.z, bv0.w, bv1.x, bv1.y, bv1.z, bv1.w,
                             bv2.x, bv2.y, bv2.z, bv2.w, bv3.x, bv3.y, bv3.z, bv3.w};
            u16 outv[16];
            #pragma unroll
            for (int j = 0; j < 16; ++j) {
                float vv = __uint_as_float(((u32)tmp[j]) << 16);
                float t2 = vv * wvf[j] + bvf[j];
                t2 = fmaxf(t2, ap * t2);
                outv[j] = f2bf(t2);
            }
            av0 = *(const uint4*)outv;
            av1 = *(const uint4*)(outv + 8);
        }
        const u16* q = WT + (size_t)(ncol0 + sr) * 256 + k0 + sh;
        uint4 bw0 = *(const uint4*)q;
        uint4 bw1 = *(const uint4*)(q + 8);
        *(uint4*)&As[sr][sh] = av0;
        *(uint4*)&As[sr][sh + 8] = av1;
        *(uint4*)&Bs[sr][sh] = bw0;
        *(uint4*)&Bs[sr][sh + 8] = bw1;
        __syncthreads();

        short8 af[4], bfr[4];
        #pragma unroll
        for (int mi = 0; mi < 4; ++mi)
            af[mi] = *(const short8*)&As[wm + mi * 16 + l16][quad * 8];
        #pragma unroll
        for (int ni = 0; ni < 4; ++ni)
            bfr[ni] = *(const short8*)&Bs[wn + ni * 16 + l16][quad * 8];
        #pragma unroll
        for (int mi = 0; mi < 4; ++mi)
            #pragma unroll
            for (int ni = 0; ni < 4; ++ni)
                acc[mi][ni] = __builtin_amdgcn_mfma_f32_16x16x32_bf16(af[mi], bfr[ni], acc[mi][ni], 0, 0, 0);
        __syncthreads();
    }

    // C/D layout: col = lane&15, row = quad*4 + reg
    #pragma unroll
    for (int ni = 0; ni < 4; ++ni) {
        int col = c0 + wn + ni * 16 + l16;
        float bv = bias[col];
        #pragma unroll
        for (int mi = 0; mi < 4; ++mi) {
            int gr = row0 + wm + mi * 16 + quad * 4;
            #pragma unroll
            for (int r = 0; r < 4; ++r) {
                if (gr + r < N_NODES)
                    outp[(size_t)(gr + r) * 256 + col] = f2bf(acc[mi][ni][r] + bv);
            }
        }
    }
}

// ---------------- fused GATv2 aggregation + column stats ----------------
// EXACT R1 (v2) body — best-measured variant (62.4-63.8 us). gat_agg is at
// its beyond-L2 traffic floor (~113 MB @ ~2 TB/s); variants v3-v8 all landed
// 62-68 us. Do not touch.

__device__ __forceinline__ void gat_load8(const int* __restrict__ col, int j, int lane,
                                          const u16* __restrict__ xlb, uint2 (&rr)[8]) {
    int cv = col[j + (lane & 7)];   // one coalesced load carries all 8 indices
    #pragma unroll
    for (int u = 0; u < 8; ++u) {
        int s = __builtin_amdgcn_readlane(cv, u);   // SGPR index -> SALU base addr
        rr[u] = *((const uint2*)(xlb + ((size_t)(u32)s << 8)) + lane);
    }
}

__device__ __forceinline__ void gat_comp8(const uint2 (&rr)[8], const float4& xrv, const float4& attv,
                                          float& denom, float4& acc) {
    #pragma unroll
    for (int u = 0; u < 8; ++u) {
        float4 a = bf2f4(rr[u]);
        float vx = a.x + xrv.x, vy = a.y + xrv.y;
        float vz = a.z + xrv.z, vw = a.w + xrv.w;
        vx = fmaxf(vx, 0.2f * vx);
        vy = fmaxf(vy, 0.2f * vy);
        vz = fmaxf(vz, 0.2f * vz);
        vw = fmaxf(vw, 0.2f * vw);
        float p = vx * attv.x + vy * attv.y + vz * attv.z + vw * attv.w;
        p = dpp_red16(p);
        float w = exp2f(p);          // att prescaled by log2(e): bare v_exp_f32
        denom += w;
        acc.x += w * a.x; acc.y += w * a.y;
        acc.z += w * a.z; acc.w += w * a.w;
    }
}

__global__ __launch_bounds__(256) void gat_agg(
    const u16* __restrict__ xlb, const u16* __restrict__ xrb,
    const int* __restrict__ rowptr, const int* __restrict__ col,
    const float* __restrict__ att_l, const float* __restrict__ bias_l,
    u16* __restrict__ hB, float* __restrict__ slot) {
    __shared__ float sred[4][520];
    int wid = threadIdx.x >> 6, lane = threadIdx.x & 63;
    int node = blockIdx.x * 4 + wid;   // 5000*4 == 20000 exactly
    const float LOG2E = 1.4426950408889634f;
    float4 attv = ((const float4*)att_l)[lane];
    attv.x *= LOG2E; attv.y *= LOG2E; attv.z *= LOG2E; attv.w *= LOG2E;
    float4 xrv = bf2f4(((const uint2*)xrb)[(size_t)node * 64 + lane]);
    int beg = __builtin_amdgcn_readfirstlane(rowptr[node]);
    int end = __builtin_amdgcn_readfirstlane(rowptr[node + 1]);

    float denom = 0.f;
    float4 acc = make_float4(0.f, 0.f, 0.f, 0.f);

    int nb = (end - beg) >> 3;   // full 8-edge batches
    int j = beg;
    uint2 rA[8], rB[8];
    if (nb > 0) gat_load8(col, j, lane, xlb, rA);
    int b = 0;
    while (b < nb) {
        if (b + 1 < nb) gat_load8(col, j + 8, lane, xlb, rB);   // prefetch next batch
        gat_comp8(rA, xrv, attv, denom, acc);
        ++b; j += 8;
        if (b < nb) {
            if (b + 1 < nb) gat_load8(col, j + 8, lane, xlb, rA);
            gat_comp8(rB, xrv, attv, denom, acc);
            ++b; j += 8;
        }
    }
    for (; j < end; ++j) {
        int s = __builtin_amdgcn_readfirstlane(col[j]);
        uint2 r = *((const uint2*)(xlb + ((size_t)(u32)s << 8)) + lane);
        float4 a = bf2f4(r);
        float vx = a.x + xrv.x, vy = a.y + xrv.y;
        float vz = a.z + xrv.z, vw = a.w + xrv.w;
        vx = fmaxf(vx, 0.2f * vx);
        vy = fmaxf(vy, 0.2f * vy);
        vz = fmaxf(vz, 0.2f * vz);
        vw = fmaxf(vw, 0.2f * vw);
        float p = vx * attv.x + vy * attv.y + vz * attv.z + vw * attv.w;
        p = dpp_red16(p);
        float w = exp2f(p);
        denom += w;
        acc.x += w * a.x; acc.y += w * a.y; acc.z += w * a.z; acc.w += w * a.w;
    }

    float inv = 1.f / denom;
    float4 b4 = ((const float4*)bias_l)[lane];
    float4 o;
    o.x = acc.x * inv + b4.x; o.y = acc.y * inv + b4.y;
    o.z = acc.z * inv + b4.z; o.w = acc.w * inv + b4.w;
    u16 ob[4] = {f2bf(o.x), f2bf(o.y), f2bf(o.z), f2bf(o.w)};
    ((uint2*)hB)[(size_t)node * 64 + lane] = *(const uint2*)ob;

    int cb2 = lane * 4;
    sred[wid][cb2 + 0] = o.x; sred[wid][cb2 + 1] = o.y;
    sred[wid][cb2 + 2] = o.z; sred[wid][cb2 + 3] = o.w;
    sred[wid][256 + cb2 + 0] = o.x * o.x; sred[wid][256 + cb2 + 1] = o.y * o.y;
    sred[wid][256 + cb2 + 2] = o.z * o.z; sred[wid][256 + cb2 + 3] = o.w * o.w;
    __syncthreads();
    int t = threadIdx.x;
    #pragma unroll
    for (int h = 0; h < 2; ++h) {
        int idx = t + h * 256;
        float s = sred[0][idx] + sred[1][idx] + sred[2][idx] + sred[3][idx];
        atomicAdd(&slot[(blockIdx.x & (NSLOT - 1)) * 512 + idx], s);
    }
}

// ---------------- pool with fused final GraphNorm+PReLU ----------------

__global__ __launch_bounds__(256) void pool_kernel(const u16* __restrict__ hB,
                                                   const int* __restrict__ batch,
                                                   const float* __restrict__ slots2,
                                                   const float* __restrict__ nw, const float* __restrict__ nb,
                                                   const float* __restrict__ na, const float* __restrict__ pa,
                                                   float* __restrict__ pooled) {
    __shared__ float accs[NBATCH][256];
    int c = threadIdx.x;
    float sum = 0.f, sq = 0.f;
    for (int s = 0; s < NSLOT; ++s) {
        sum += slots2[s * 512 + c];
        sq += slots2[s * 512 + 256 + c];
    }
    const float invn = 1.f / (float)N_NODES;
    float mean = sum * invn, Eh2 = sq * invn;
    float a = na[c];
    float var = Eh2 - (2.f * a - a * a) * mean * mean;
    float wc = nw[c] * rsqrtf(var + GEPS);
    float bb = nb[c] - a * mean * wc;
    float ap = pa[2];

    #pragma unroll
    for (int b = 0; b < NBATCH; ++b) accs[b][c] = 0.f;
    int r0 = blockIdx.x * 100;
    int r1 = min(N_NODES, r0 + 100);
    for (int i = r0; i < r1; ++i) {
        float v = __uint_as_float(((u32)hB[(size_t)i * 256 + c]) << 16);
        v = v * wc + bb;
        v = fmaxf(v, ap * v);
        accs[batch[i]][c] += v;
    }
    int bmin = batch[r0], bmax = batch[r1 - 1];
    for (int b = bmin; b <= bmax; ++b) atomicAdd(&pooled[b * 256 + c], accs[b][c]);
}

// ---------------- FC with fused pooled GraphNorm: 16 blocks ----------------

__global__ __launch_bounds__(256) void fc_kernel(const float* __restrict__ pooled,
                                                 const float* __restrict__ nw, const float* __restrict__ nb,
                                                 const float* __restrict__ na,
                                                 const float* __restrict__ fcW, const float* __restrict__ fcb,
                                                 float* __restrict__ out) {
    __shared__ float pnl[256];
    __shared__ float part[128];
    int b = blockIdx.x;
    int t = threadIdx.x;
    float mean = 0.f, sq = 0.f;
    #pragma unroll
    for (int i = 0; i < NBATCH; ++i) {
        float v = pooled[i * 256 + t];
        mean += v; sq += v * v;
    }
    mean *= (1.f / NBATCH); sq *= (1.f / NBATCH);
    float a = na[t];
    float var = sq - (2.f * a - a * a) * mean * mean;
    float wc = nw[t] * rsqrtf(var + GEPS);
    float bb = nb[t] - a * mean * wc;
    pnl[t] = pooled[b * 256 + t] * wc + bb;
    __syncthreads();
    int o = t & 127, half = t >> 7;
    float s = 0.f;
    int kbase = half * 128;
    #pragma unroll 8
    for (int k = 0; k < 128; ++k)
        s += pnl[kbase + k] * fcW[(kbase + k) * 128 + o];
    if (half == 1) part[o] = s;
    __syncthreads();
    if (half == 0) out[b * 128 + o] = s + part[o] + fcb[o];
}

// ---------------- launch ----------------

extern "C" void kernel_launch(void* const* d_in, const int* in_sizes, int n_in,
                              void* d_out, int out_size, void* d_ws, size_t ws_size,
                              hipStream_t stream) {
    const float* x    = (const float*)d_in[0];
    const int*   ei   = (const int*)d_in[1];
    const int*   batch= (const int*)d_in[2];
    const float* Wl   = (const float*)d_in[3];
    const float* bl   = (const float*)d_in[4];
    const float* Wr   = (const float*)d_in[5];
    const float* br   = (const float*)d_in[6];
    const float* att  = (const float*)d_in[7];
    const float* cb   = (const float*)d_in[8];
    const float* pa   = (const float*)d_in[9];
    const float* nw   = (const float*)d_in[10];
    const float* nb   = (const float*)d_in[11];
    const float* na   = (const float*)d_in[12];
    const float* fcW  = (const float*)d_in[13];
    const float* fcb  = (const float*)d_in[14];
    float* out = (float*)d_out;

    char* ws = (char*)d_ws;
    size_t off = 0;
    auto carve = [&](size_t bytes) -> void* {
        void* p = (void*)(ws + off);
        off += (bytes + 255) & ~(size_t)255;
        return p;
    };
    // zero-span region (hipMemsetAsync zeroes [rowptr, end-of-pooled))
    size_t z0 = off;
    int*   rowptr = (int*)carve((N_NODES + 1) * sizeof(int));
    float* slots  = (float*)carve((size_t)NLAYER * NSLOT * 512 * sizeof(float));
    float* pooled = (float*)carve(NBATCH * HC * sizeof(float));
    size_t z1 = off;
    // non-zeroed scratch
    int*   cursor = (int*)carve(N_NODES * sizeof(int));
    int*   colidx = (int*)carve((size_t)ETOT * sizeof(int));
    u16*   xlb    = (u16*)carve((size_t)N_NODES * HC * sizeof(u16));
    u16*   xrb    = (u16*)carve((size_t)N_NODES * HC * sizeof(u16));
    u16*   hB     = (u16*)carve((size_t)N_NODES * HC * sizeof(u16));
    u16*   xbf    = (u16*)carve((size_t)N_NODES * HC * sizeof(u16));
    u16*   WT     = (u16*)carve((size_t)NLAYER * 512 * 256 * sizeof(u16));

    const int* srcp = ei;
    const int* dstp = ei + N_EDGES;

    hipMemsetAsync(ws + z0, 0, z1 - z0, stream);
    prep<<<2009, 256, 0, stream>>>(x, xbf, Wl, Wr, WT, dstp, rowptr);
    scan_excl<<<1, 1024, 0, stream>>>(rowptr, cursor);

    for (int l = 0; l < NLAYER; ++l) {
        const u16* Asrc = (l == 0) ? xbf : hB;
        const float* slots_prev = slots + (size_t)((l > 0) ? (l - 1) : 0) * NSLOT * 512;
        int grid = (l == 0) ? (640 + 645) : 640;   // l=0 carries scatter rider blocks
        gemm_mfma<<<grid, 256, 0, stream>>>(Asrc, slots_prev, nw, nb, na, pa,
                                            (l > 0) ? (l - 1) : 0, (l > 0) ? 1 : 0,
                                            WT + (size_t)l * 512 * 256,
                                            bl + l * 256, br + l * 256, xlb, xrb,
                                            srcp, dstp, cursor, colidx);
        gat_agg<<<5000, 256, 0, stream>>>(xlb, xrb, rowptr, colidx, att + l * 256, cb + l * 256,
                                          hB, slots + (size_t)l * NSLOT * 512);
    }
    pool_kernel<<<200, 256, 0, stream>>>(hB, batch, slots + (size_t)2 * NSLOT * 512,
                                         nw, nb, na, pa, pooled);
    fc_kernel<<<NBATCH, 256, 0, stream>>>(pooled, nw, nb, na, fcW, fcb, out);
}